// Round 4
// baseline (484.846 us; speedup 1.0000x reference)
//
#include <hip/hip_runtime.h>
#include <hip/hip_bf16.h>
#include <math.h>

#define HIDDEN 2048
#define INTER 1024
#define NEXP 64
#define TOPK 8
#define NTOK 512

#define MT 96                 // M tile rows (6 x 16)
#define AWS_ROWS (NTOK * TOPK + 128)

typedef float floatx4 __attribute__((ext_vector_type(4)));
typedef short shortx8 __attribute__((ext_vector_type(8)));

__device__ __forceinline__ unsigned short bfbits(float f) {
    union { __hip_bfloat16 h; unsigned short u; } c;
    c.h = __float2bfloat16(f);
    return c.u;
}

// ---------------- x fp32 -> bf16 pre-convert ----------------
__global__ void xcvt_kernel(const float* __restrict__ x, __hip_bfloat16* __restrict__ xbf) {
    int i = blockIdx.x * blockDim.x + threadIdx.x;   // one float4 per thread
    float4 v = ((const float4*)x)[i];
    uint2 r;
    r.x = ((unsigned)bfbits(v.y) << 16) | (unsigned)bfbits(v.x);
    r.y = ((unsigned)bfbits(v.w) << 16) | (unsigned)bfbits(v.z);
    ((uint2*)xbf)[i] = r;
}

// ---------------- Router + top-8 + softmax ----------------
__global__ void router_topk_kernel(const float* __restrict__ x,
                                   const float* __restrict__ wr,
                                   int* __restrict__ topk_idx,
                                   float* __restrict__ gates) {
    const int t = blockIdx.x;
    const int lane = threadIdx.x;
    __shared__ float sx[HIDDEN];
    for (int i = lane; i < HIDDEN / 4; i += 64)
        *(float4*)&sx[i * 4] = *(const float4*)(x + (size_t)t * HIDDEN + i * 4);
    __syncthreads();

    float a0 = 0.f, a1 = 0.f, a2 = 0.f, a3 = 0.f;
#pragma unroll 4
    for (int d = 0; d < HIDDEN; d += 4) {
        a0 = fmaf(sx[d + 0], wr[(d + 0) * NEXP + lane], a0);
        a1 = fmaf(sx[d + 1], wr[(d + 1) * NEXP + lane], a1);
        a2 = fmaf(sx[d + 2], wr[(d + 2) * NEXP + lane], a2);
        a3 = fmaf(sx[d + 3], wr[(d + 3) * NEXP + lane], a3);
    }
    float cur = (a0 + a1) + (a2 + a3);

    float topv[TOPK];
    int topi[TOPK];
#pragma unroll
    for (int k = 0; k < TOPK; ++k) {
        float bv = cur;
        int bi = lane;
#pragma unroll
        for (int off = 32; off > 0; off >>= 1) {
            float ov = __shfl_xor(bv, off, 64);
            int oi = __shfl_xor(bi, off, 64);
            if (ov > bv || (ov == bv && oi < bi)) { bv = ov; bi = oi; }
        }
        topv[k] = bv;
        topi[k] = bi;
        if (lane == bi) cur = -INFINITY;
    }
    if (lane == 0) {
        float m = topv[0];
        float ex[TOPK], s = 0.f;
#pragma unroll
        for (int k = 0; k < TOPK; ++k) { ex[k] = __expf(topv[k] - m); s += ex[k]; }
        float inv = 1.f / s;
#pragma unroll
        for (int k = 0; k < TOPK; ++k) {
            gates[t * TOPK + k] = ex[k] * inv;
            topk_idx[t * TOPK + k] = topi[k];
        }
    }
}

// ---------------- Deterministic bucket build ----------------
__global__ void build_buckets_kernel(const int* __restrict__ topk_idx,
                                     const float* __restrict__ gates,
                                     int* __restrict__ bucket_tok,
                                     float* __restrict__ bucket_gate,
                                     int* __restrict__ count) {
    const int e = blockIdx.x;
    const int tid = threadIdx.x;
    __shared__ int scan[256];
    const int t0 = tid * 2;
    int f0 = 0, f1 = 0;
    float g0 = 0.f, g1 = 0.f;
#pragma unroll
    for (int k = 0; k < TOPK; ++k) {
        if (topk_idx[t0 * TOPK + k] == e) { f0 = 1; g0 = gates[t0 * TOPK + k]; }
        if (topk_idx[(t0 + 1) * TOPK + k] == e) { f1 = 1; g1 = gates[(t0 + 1) * TOPK + k]; }
    }
    int s = f0 + f1;
    scan[tid] = s;
    __syncthreads();
    for (int off = 1; off < 256; off <<= 1) {
        int add = (tid >= off) ? scan[tid - off] : 0;
        __syncthreads();
        scan[tid] += add;
        __syncthreads();
    }
    int excl = scan[tid] - s;
    if (f0) { bucket_tok[e * NTOK + excl] = t0; bucket_gate[e * NTOK + excl] = g0; }
    if (f1) { bucket_tok[e * NTOK + excl + f0] = t0 + 1; bucket_gate[e * NTOK + excl + f0] = g1; }
    if (tid == 255) count[e] = scan[255];
}

__global__ void base_scan_kernel(const int* __restrict__ count, int* __restrict__ base) {
    if (threadIdx.x == 0) {
        int acc = 0;
        for (int e = 0; e < NEXP; ++e) { base[e] = acc; acc += count[e]; }
    }
}

// ---------------- Fused gate/up + SiLU (bf16 MFMA, zero-LDS) ----------------
// grid 512: e = bid&63 (same expert -> same XCD), chunk = bid>>6 covers
// 128 gate cols + 128 up cols. 4 waves; wave w owns col-subtiles
// {2w,2w+1} of gate and of up. Fragments loaded direct from global:
//   A[lane] = xbf[tok(ms*16+r16)][k0+8q .. +7]   (uint4, L2-resident)
//   B[lane] = W[k0+8q+j][col(sub*16+r16)]        (8 strided dwords, HBM stream)
// Same (q,j)->k convention both operands (slot permutation cancels; R3-verified).
__global__ __launch_bounds__(256, 2) void gateup_mfma(
    const __hip_bfloat16* __restrict__ xbf, const float* __restrict__ wg,
    const float* __restrict__ wu, const int* __restrict__ bucket_tok,
    const float* __restrict__ bucket_gate, const int* __restrict__ count,
    const int* __restrict__ base, __hip_bfloat16* __restrict__ Aws) {
    const int e = blockIdx.x & 63;
    const int c0 = (blockIdx.x >> 6) * 128;
    const int n = count[e];
    if (n == 0) return;
    const int b0 = base[e];

    const int tid = threadIdx.x;
    const int lane = tid & 63, w = tid >> 6;
    const int q = lane >> 4, r16 = lane & 15;

    const float* wbase[4];
    {
        const float* wge = wg + (size_t)e * HIDDEN * INTER + c0;
        const float* wue = wu + (size_t)e * HIDDEN * INTER + c0;
        wbase[0] = wge + (2 * w + 0) * 16 + r16 + (size_t)(8 * q) * INTER;
        wbase[1] = wge + (2 * w + 1) * 16 + r16 + (size_t)(8 * q) * INTER;
        wbase[2] = wue + (2 * w + 0) * 16 + r16 + (size_t)(8 * q) * INTER;
        wbase[3] = wue + (2 * w + 1) * 16 + r16 + (size_t)(8 * q) * INTER;
    }

    for (int m0 = 0; m0 < n; m0 += MT) {
        const __hip_bfloat16* xrow[6];
#pragma unroll
        for (int ms = 0; ms < 6; ++ms) {
            int p = m0 + ms * 16 + r16;
            int tk = (p < n) ? bucket_tok[e * NTOK + p] : 0;
            xrow[ms] = xbf + (size_t)tk * HIDDEN + 8 * q;
        }

        floatx4 acc[6][4];
#pragma unroll
        for (int ms = 0; ms < 6; ++ms)
#pragma unroll
            for (int s = 0; s < 4; ++s) acc[ms][s] = (floatx4){0.f, 0.f, 0.f, 0.f};

        float wa[4][8], wb[4][8];
        uint4 xr[6];

        auto LOADW_A = [&](int kt) {
#pragma unroll
            for (int s = 0; s < 4; ++s) {
                const float* p = wbase[s] + (size_t)kt * 32 * INTER;
#pragma unroll
                for (int j = 0; j < 8; ++j) wa[s][j] = p[(size_t)j * INTER];
            }
        };
        auto LOADW_B = [&](int kt) {
#pragma unroll
            for (int s = 0; s < 4; ++s) {
                const float* p = wbase[s] + (size_t)kt * 32 * INTER;
#pragma unroll
                for (int j = 0; j < 8; ++j) wb[s][j] = p[(size_t)j * INTER];
            }
        };
        auto LOADX = [&](int kt) {
#pragma unroll
            for (int ms = 0; ms < 6; ++ms)
                xr[ms] = *(const uint4*)(xrow[ms] + kt * 32);
        };
        auto STEP = [&](float (&ws)[4][8]) {
            shortx8 bw[4];
#pragma unroll
            for (int s = 0; s < 4; ++s) {
                shortx8 t;
#pragma unroll
                for (int j = 0; j < 8; ++j) t[j] = (short)bfbits(ws[s][j]);
                bw[s] = t;
            }
#pragma unroll
            for (int ms = 0; ms < 6; ++ms) {
                shortx8 af = *(shortx8*)&xr[ms];
#pragma unroll
                for (int s = 0; s < 4; ++s)
                    acc[ms][s] = __builtin_amdgcn_mfma_f32_16x16x32_bf16(af, bw[s], acc[ms][s], 0, 0, 0);
            }
        };

        LOADW_A(0);
        for (int k2 = 0; k2 < 32; ++k2) {
            LOADX(2 * k2);
            LOADW_B(2 * k2 + 1);
            STEP(wa);
            LOADX(2 * k2 + 1);
            if (k2 < 31) LOADW_A(2 * k2 + 2);
            STEP(wb);
        }

        // epilogue: A = silu(h) * u * gate, bf16
        // C layout: col = lane&15, row = 4*(lane>>4) + reg (m89-verified)
#pragma unroll
        for (int ms = 0; ms < 6; ++ms) {
#pragma unroll
            for (int j = 0; j < 2; ++j) {
                floatx4 h4 = acc[ms][j], u4 = acc[ms][j + 2];
#pragma unroll
                for (int rr = 0; rr < 4; ++rr) {
                    int ml = ms * 16 + 4 * q + rr;
                    int p = m0 + ml;
                    if (p < n) {
                        float gt = bucket_gate[e * NTOK + p];
                        float hv = h4[rr];
                        float av = hv / (1.f + __expf(-hv)) * u4[rr] * gt;
                        int col = c0 + (2 * w + j) * 16 + r16;
                        Aws[(size_t)(b0 + p) * INTER + col] = __float2bfloat16(av);
                    }
                }
            }
        }
    }
}

// ---------------- Down projection (bf16 MFMA, zero-LDS) + scatter-add ----------------
// grid 512: e = bid&63, chunk = bid>>6 covers 256 out cols; wave w owns subs 4w..4w+3.
__global__ __launch_bounds__(256, 2) void down_mfma(
    const __hip_bfloat16* __restrict__ Aws, const float* __restrict__ wd,
    const int* __restrict__ bucket_tok, const int* __restrict__ count,
    const int* __restrict__ base, float* __restrict__ out) {
    const int e = blockIdx.x & 63;
    const int c0 = (blockIdx.x >> 6) * 256;
    const int n = count[e];
    if (n == 0) return;
    const int b0 = base[e];

    const int tid = threadIdx.x;
    const int lane = tid & 63, w = tid >> 6;
    const int q = lane >> 4, r16 = lane & 15;

    const float* wbase[4];
    {
        const float* wde = wd + (size_t)e * INTER * HIDDEN + c0;
#pragma unroll
        for (int s = 0; s < 4; ++s)
            wbase[s] = wde + (4 * w + s) * 16 + r16 + (size_t)(8 * q) * HIDDEN;
    }

    for (int m0 = 0; m0 < n; m0 += MT) {
        const __hip_bfloat16* arow[6];
#pragma unroll
        for (int ms = 0; ms < 6; ++ms)
            arow[ms] = Aws + (size_t)(b0 + m0 + ms * 16 + r16) * INTER + 8 * q;

        floatx4 acc[6][4];
#pragma unroll
        for (int ms = 0; ms < 6; ++ms)
#pragma unroll
            for (int s = 0; s < 4; ++s) acc[ms][s] = (floatx4){0.f, 0.f, 0.f, 0.f};

        float wa[4][8], wb[4][8];
        uint4 ar[6];

        auto LOADW_A = [&](int kt) {
#pragma unroll
            for (int s = 0; s < 4; ++s) {
                const float* p = wbase[s] + (size_t)kt * 32 * HIDDEN;
#pragma unroll
                for (int j = 0; j < 8; ++j) wa[s][j] = p[(size_t)j * HIDDEN];
            }
        };
        auto LOADW_B = [&](int kt) {
#pragma unroll
            for (int s = 0; s < 4; ++s) {
                const float* p = wbase[s] + (size_t)kt * 32 * HIDDEN;
#pragma unroll
                for (int j = 0; j < 8; ++j) wb[s][j] = p[(size_t)j * HIDDEN];
            }
        };
        auto LOADA = [&](int kt) {
#pragma unroll
            for (int ms = 0; ms < 6; ++ms)
                ar[ms] = *(const uint4*)(arow[ms] + kt * 32);
        };
        auto STEP = [&](float (&ws)[4][8]) {
            shortx8 bw[4];
#pragma unroll
            for (int s = 0; s < 4; ++s) {
                shortx8 t;
#pragma unroll
                for (int j = 0; j < 8; ++j) t[j] = (short)bfbits(ws[s][j]);
                bw[s] = t;
            }
#pragma unroll
            for (int ms = 0; ms < 6; ++ms) {
                shortx8 af = *(shortx8*)&ar[ms];
#pragma unroll
                for (int s = 0; s < 4; ++s)
                    acc[ms][s] = __builtin_amdgcn_mfma_f32_16x16x32_bf16(af, bw[s], acc[ms][s], 0, 0, 0);
            }
        };

        LOADW_A(0);
        for (int k2 = 0; k2 < 16; ++k2) {
            LOADA(2 * k2);
            LOADW_B(2 * k2 + 1);
            STEP(wa);
            LOADA(2 * k2 + 1);
            if (k2 < 15) LOADW_A(2 * k2 + 2);
            STEP(wb);
        }

#pragma unroll
        for (int ms = 0; ms < 6; ++ms) {
#pragma unroll
            for (int rr = 0; rr < 4; ++rr) {
                int ml = ms * 16 + 4 * q + rr;
                int p = m0 + ml;
                if (p < n) {
                    int tok = bucket_tok[e * NTOK + p];
                    float* orow = out + (size_t)tok * HIDDEN;
#pragma unroll
                    for (int s = 0; s < 4; ++s) {
                        int col = c0 + (4 * w + s) * 16 + r16;
                        unsafeAtomicAdd(&orow[col], acc[ms][s][rr]);
                    }
                }
            }
        }
    }
}

extern "C" void kernel_launch(void* const* d_in, const int* in_sizes, int n_in,
                              void* d_out, int out_size, void* d_ws, size_t ws_size,
                              hipStream_t stream) {
    const float* x = (const float*)d_in[0];
    const float* wr = (const float*)d_in[1];
    const float* wg = (const float*)d_in[2];
    const float* wu = (const float*)d_in[3];
    const float* wd = (const float*)d_in[4];
    float* out = (float*)d_out;

    char* ws = (char*)d_ws;
    size_t off = 0;
    auto alloc = [&](size_t bytes) {
        void* p = ws + off;
        off = (off + bytes + 255) & ~(size_t)255;
        return p;
    };
    int* topk_idx = (int*)alloc(NTOK * TOPK * sizeof(int));
    float* gates = (float*)alloc(NTOK * TOPK * sizeof(float));
    int* bucket_tok = (int*)alloc(NEXP * NTOK * sizeof(int));
    float* bucket_gate = (float*)alloc(NEXP * NTOK * sizeof(float));
    int* count = (int*)alloc(NEXP * sizeof(int));
    int* base = (int*)alloc(NEXP * sizeof(int));
    __hip_bfloat16* Aws = (__hip_bfloat16*)alloc((size_t)AWS_ROWS * INTER * sizeof(__hip_bfloat16));
    __hip_bfloat16* xbf = (__hip_bfloat16*)alloc((size_t)NTOK * HIDDEN * sizeof(__hip_bfloat16));
    (void)ws_size;

    hipMemsetAsync(d_out, 0, (size_t)NTOK * HIDDEN * sizeof(float), stream);

    xcvt_kernel<<<NTOK * HIDDEN / 4 / 256, 256, 0, stream>>>(x, xbf);
    router_topk_kernel<<<NTOK, 64, 0, stream>>>(x, wr, topk_idx, gates);
    build_buckets_kernel<<<NEXP, 256, 0, stream>>>(topk_idx, gates, bucket_tok, bucket_gate, count);
    base_scan_kernel<<<1, 64, 0, stream>>>(count, base);
    gateup_mfma<<<NEXP * 8, 256, 0, stream>>>(xbf, wg, wu, bucket_tok, bucket_gate, count, base, Aws);
    down_mfma<<<NEXP * 8, 256, 0, stream>>>(Aws, wd, bucket_tok, count, base, out);
}

// Round 5
// 437.744 us; speedup vs baseline: 1.1076x; 1.1076x over previous
//
#include <hip/hip_runtime.h>
#include <hip/hip_bf16.h>
#include <math.h>

#define HIDDEN 2048
#define INTER 1024
#define NEXP 64
#define TOPK 8
#define NTOK 512

#define MT 96                  // M tile rows (6 x 16)
#define ROWB 80                // LDS row stride bytes (32 bf16 = 64B + 16B pad; mult of 16)
#define WR 128                 // W^T rows per buffer (cols covered per block)
#define WTB (WR * ROWB)        // 10240 B
#define XOFF WTB
#define BUFB (WTB + MT * ROWB) // 17920 B per buffer
#define AWS_ROWS (NTOK * TOPK + 128)

typedef float floatx4 __attribute__((ext_vector_type(4)));
typedef short shortx8 __attribute__((ext_vector_type(8)));

__device__ __forceinline__ unsigned short bfbits(float f) {
    union { __hip_bfloat16 h; unsigned short u; } c;
    c.h = __float2bfloat16(f);
    return c.u;
}
// pack 4 floats (k-ascending) -> 8B of bf16, k-ascending in memory
__device__ __forceinline__ uint2 pack4(float a, float b, float c, float d) {
    uint2 r;
    r.x = ((unsigned)bfbits(b) << 16) | (unsigned)bfbits(a);
    r.y = ((unsigned)bfbits(d) << 16) | (unsigned)bfbits(c);
    return r;
}

// ---------------- x fp32 -> bf16 pre-convert ----------------
__global__ void xcvt_kernel(const float* __restrict__ x, __hip_bfloat16* __restrict__ xbf) {
    int i = blockIdx.x * blockDim.x + threadIdx.x;
    float4 v = ((const float4*)x)[i];
    ((uint2*)xbf)[i] = pack4(v.x, v.y, v.z, v.w);
}

// ---------------- Router + top-8 + softmax ----------------
__global__ void router_topk_kernel(const float* __restrict__ x,
                                   const float* __restrict__ wr,
                                   int* __restrict__ topk_idx,
                                   float* __restrict__ gates) {
    const int t = blockIdx.x;
    const int lane = threadIdx.x;
    __shared__ float sx[HIDDEN];
    for (int i = lane; i < HIDDEN / 4; i += 64)
        *(float4*)&sx[i * 4] = *(const float4*)(x + (size_t)t * HIDDEN + i * 4);
    __syncthreads();

    float a0 = 0.f, a1 = 0.f, a2 = 0.f, a3 = 0.f;
#pragma unroll 4
    for (int d = 0; d < HIDDEN; d += 4) {
        a0 = fmaf(sx[d + 0], wr[(d + 0) * NEXP + lane], a0);
        a1 = fmaf(sx[d + 1], wr[(d + 1) * NEXP + lane], a1);
        a2 = fmaf(sx[d + 2], wr[(d + 2) * NEXP + lane], a2);
        a3 = fmaf(sx[d + 3], wr[(d + 3) * NEXP + lane], a3);
    }
    float cur = (a0 + a1) + (a2 + a3);

    float topv[TOPK];
    int topi[TOPK];
#pragma unroll
    for (int k = 0; k < TOPK; ++k) {
        float bv = cur;
        int bi = lane;
#pragma unroll
        for (int off = 32; off > 0; off >>= 1) {
            float ov = __shfl_xor(bv, off, 64);
            int oi = __shfl_xor(bi, off, 64);
            if (ov > bv || (ov == bv && oi < bi)) { bv = ov; bi = oi; }
        }
        topv[k] = bv;
        topi[k] = bi;
        if (lane == bi) cur = -INFINITY;
    }
    if (lane == 0) {
        float m = topv[0];
        float ex[TOPK], s = 0.f;
#pragma unroll
        for (int k = 0; k < TOPK; ++k) { ex[k] = __expf(topv[k] - m); s += ex[k]; }
        float inv = 1.f / s;
#pragma unroll
        for (int k = 0; k < TOPK; ++k) {
            gates[t * TOPK + k] = ex[k] * inv;
            topk_idx[t * TOPK + k] = topi[k];
        }
    }
}

// ---------------- Deterministic bucket build ----------------
__global__ void build_buckets_kernel(const int* __restrict__ topk_idx,
                                     const float* __restrict__ gates,
                                     int* __restrict__ bucket_tok,
                                     float* __restrict__ bucket_gate,
                                     int* __restrict__ count) {
    const int e = blockIdx.x;
    const int tid = threadIdx.x;
    __shared__ int scan[256];
    const int t0 = tid * 2;
    int f0 = 0, f1 = 0;
    float g0 = 0.f, g1 = 0.f;
#pragma unroll
    for (int k = 0; k < TOPK; ++k) {
        if (topk_idx[t0 * TOPK + k] == e) { f0 = 1; g0 = gates[t0 * TOPK + k]; }
        if (topk_idx[(t0 + 1) * TOPK + k] == e) { f1 = 1; g1 = gates[(t0 + 1) * TOPK + k]; }
    }
    int s = f0 + f1;
    scan[tid] = s;
    __syncthreads();
    for (int off = 1; off < 256; off <<= 1) {
        int add = (tid >= off) ? scan[tid - off] : 0;
        __syncthreads();
        scan[tid] += add;
        __syncthreads();
    }
    int excl = scan[tid] - s;
    if (f0) { bucket_tok[e * NTOK + excl] = t0; bucket_gate[e * NTOK + excl] = g0; }
    if (f1) { bucket_tok[e * NTOK + excl + f0] = t0 + 1; bucket_gate[e * NTOK + excl + f0] = g1; }
    if (tid == 255) count[e] = scan[255];
}

__global__ void base_scan_kernel(const int* __restrict__ count, int* __restrict__ base) {
    if (threadIdx.x == 0) {
        int acc = 0;
        for (int e = 0; e < NEXP; ++e) { base[e] = acc; acc += count[e]; }
    }
}

// ---------------- Fused gate/up + SiLU (bf16 MFMA) ----------------
// grid 1024: e = bid&63 (same expert -> same XCD), chunk = bid>>6 covers
// 64 gate cols + 64 up cols. LDS W^T rows: 0..63 gate, 64..127 up, 32 bf16
// k-contiguous per row. Wave w: B-subtiles {gate w, up w}. 4 blocks/CU.
// W staged coalesced: 4x dwordx4 along rows (k=l0..l0+3, 4 cols) -> pack ->
// 4x ds_write_b64 transposed. Fragment recipe identical to R3 (verified).
__global__ __launch_bounds__(256, 4) void gateup_mfma(
    const __hip_bfloat16* __restrict__ xbf, const float* __restrict__ wg,
    const float* __restrict__ wu, const int* __restrict__ bucket_tok,
    const float* __restrict__ bucket_gate, const int* __restrict__ count,
    const int* __restrict__ base, __hip_bfloat16* __restrict__ Aws) {
    const int e = blockIdx.x & 63;
    const int c0 = (blockIdx.x >> 6) * 64;
    const int n = count[e];
    if (n == 0) return;
    const int b0 = base[e];

    __shared__ char smem[2 * BUFB] __attribute__((aligned(16)));

    const int tid = threadIdx.x;
    const int lane = tid & 63, w = tid >> 6;
    const int q = lane >> 4, r16 = lane & 15;

    // W staging decode
    const int wk = tid >> 5;          // 0..7 -> k quad l0 = wk*4
    const int wc4 = (tid & 31) * 4;   // LDS row group 0..124 (0..63 gate, 64..127 up)
    const float* wsrc0 =
        ((wc4 < 64) ? (wg + (size_t)e * HIDDEN * INTER + c0 + wc4)
                    : (wu + (size_t)e * HIDDEN * INTER + c0 + (wc4 - 64)))
        + (size_t)(wk * 4) * INTER;
    const unsigned wldso = (unsigned)(wc4 * ROWB + wk * 8);

    // X staging decode (96 rows x 4 chunks of 16B)
    const int xrow0 = tid >> 2, xch0 = (tid & 3);
    const int xrow1 = 64 + (tid >> 2), xch1 = (tid & 3);
    const bool xv1 = tid < 128;
    const unsigned xldso0 = (unsigned)(XOFF + xrow0 * ROWB + xch0 * 16);
    const unsigned xldso1 = (unsigned)(XOFF + xrow1 * ROWB + xch1 * 16);

    for (int m0 = 0; m0 < n; m0 += MT) {
        int p0 = m0 + xrow0;
        int tk0 = (p0 < n) ? bucket_tok[e * NTOK + p0] : 0;
        const __hip_bfloat16* xp0 = xbf + (size_t)tk0 * HIDDEN + xch0 * 8;
        int p1 = m0 + xrow1;
        int tk1 = (xv1 && p1 < n) ? bucket_tok[e * NTOK + p1] : 0;
        const __hip_bfloat16* xp1 = xbf + (size_t)tk1 * HIDDEN + xch1 * 8;
        const float* wp = wsrc0;

        floatx4 acc[6][2];
#pragma unroll
        for (int ms = 0; ms < 6; ++ms)
#pragma unroll
            for (int s = 0; s < 2; ++s) acc[ms][s] = (floatx4){0.f, 0.f, 0.f, 0.f};

        float4 wreg[4];
        uint4 xr0, xr1;
#pragma unroll
        for (int i = 0; i < 4; ++i) wreg[i] = *(const float4*)(wp + (size_t)i * INTER);
        wp += (size_t)32 * INTER;
        xr0 = *(const uint4*)xp0; xp0 += 32;
        if (xv1) { xr1 = *(const uint4*)xp1; xp1 += 32; }

        for (int kt = 0; kt < HIDDEN / 32; ++kt) {
            char* buf = smem + (kt & 1) * BUFB;
            // ---- write phase (compiler inserts vmcnt waits) ----
#pragma unroll
            for (int cc = 0; cc < 4; ++cc)
                *(uint2*)(buf + wldso + cc * ROWB) =
                    pack4(wreg[0][cc], wreg[1][cc], wreg[2][cc], wreg[3][cc]);
            *(uint4*)(buf + xldso0) = xr0;
            if (xv1) *(uint4*)(buf + xldso1) = xr1;
            __syncthreads();
            // ---- issue next K-tile's loads (fly under MFMA) ----
            if (kt + 1 < HIDDEN / 32) {
#pragma unroll
                for (int i = 0; i < 4; ++i) wreg[i] = *(const float4*)(wp + (size_t)i * INTER);
                wp += (size_t)32 * INTER;
                xr0 = *(const uint4*)xp0; xp0 += 32;
                if (xv1) { xr1 = *(const uint4*)xp1; xp1 += 32; }
            }
            // ---- fragments (R3-verified convention) ----
            shortx8 bfr[2];
            bfr[0] = *(const shortx8*)(buf + (w * 16 + r16) * ROWB + q * 16);
            bfr[1] = *(const shortx8*)(buf + ((64 + w * 16) + r16) * ROWB + q * 16);
            shortx8 afr[6];
#pragma unroll
            for (int ms = 0; ms < 6; ++ms)
                afr[ms] = *(const shortx8*)(buf + XOFF + (ms * 16 + r16) * ROWB + q * 16);
#pragma unroll
            for (int ms = 0; ms < 6; ++ms) {
                acc[ms][0] = __builtin_amdgcn_mfma_f32_16x16x32_bf16(afr[ms], bfr[0], acc[ms][0], 0, 0, 0);
                acc[ms][1] = __builtin_amdgcn_mfma_f32_16x16x32_bf16(afr[ms], bfr[1], acc[ms][1], 0, 0, 0);
            }
            __syncthreads();
        }
        // ---- epilogue: A = silu(h) * u * gate, bf16 ----
        // C layout: col = lane&15, row = 4*(lane>>4) + reg (m89-verified)
#pragma unroll
        for (int ms = 0; ms < 6; ++ms) {
            floatx4 h4 = acc[ms][0], u4 = acc[ms][1];
#pragma unroll
            for (int rr = 0; rr < 4; ++rr) {
                int ml = ms * 16 + 4 * q + rr;
                int p = m0 + ml;
                if (p < n) {
                    float gt = bucket_gate[e * NTOK + p];
                    float hv = h4[rr];
                    float av = hv / (1.f + __expf(-hv)) * u4[rr] * gt;
                    int col = c0 + w * 16 + r16;
                    Aws[(size_t)(b0 + p) * INTER + col] = __float2bfloat16(av);
                }
            }
        }
    }
}

// ---------------- Down projection (bf16 MFMA) + scatter-add ----------------
// grid 1024: e = bid&63, chunk = bid>>6 covers 128 out cols. Wave w owns
// col-subtiles {2w, 2w+1}. Same staging scheme as gateup.
__global__ __launch_bounds__(256, 4) void down_mfma(
    const __hip_bfloat16* __restrict__ Aws, const float* __restrict__ wd,
    const int* __restrict__ bucket_tok, const int* __restrict__ count,
    const int* __restrict__ base, float* __restrict__ out) {
    const int e = blockIdx.x & 63;
    const int c0 = (blockIdx.x >> 6) * 128;
    const int n = count[e];
    if (n == 0) return;
    const int b0 = base[e];

    __shared__ char smem[2 * BUFB] __attribute__((aligned(16)));

    const int tid = threadIdx.x;
    const int lane = tid & 63, w = tid >> 6;
    const int q = lane >> 4, r16 = lane & 15;

    const int wk = tid >> 5;
    const int wc4 = (tid & 31) * 4;   // LDS row group = out-col offset 0..124
    const float* wsrc0 = wd + (size_t)e * INTER * HIDDEN + c0 + wc4 + (size_t)(wk * 4) * HIDDEN;
    const unsigned wldso = (unsigned)(wc4 * ROWB + wk * 8);

    const int xrow0 = tid >> 2, xch0 = (tid & 3);
    const int xrow1 = 64 + (tid >> 2), xch1 = (tid & 3);
    const bool xv1 = tid < 128;
    const unsigned xldso0 = (unsigned)(XOFF + xrow0 * ROWB + xch0 * 16);
    const unsigned xldso1 = (unsigned)(XOFF + xrow1 * ROWB + xch1 * 16);

    for (int m0 = 0; m0 < n; m0 += MT) {
        const __hip_bfloat16* ap0 = Aws + (size_t)(b0 + m0 + xrow0) * INTER + xch0 * 8;
        const __hip_bfloat16* ap1 = Aws + (size_t)(b0 + m0 + xrow1) * INTER + xch1 * 8;
        const float* wp = wsrc0;

        floatx4 acc[6][2];
#pragma unroll
        for (int ms = 0; ms < 6; ++ms)
#pragma unroll
            for (int s = 0; s < 2; ++s) acc[ms][s] = (floatx4){0.f, 0.f, 0.f, 0.f};

        float4 wreg[4];
        uint4 ar0, ar1;
#pragma unroll
        for (int i = 0; i < 4; ++i) wreg[i] = *(const float4*)(wp + (size_t)i * HIDDEN);
        wp += (size_t)32 * HIDDEN;
        ar0 = *(const uint4*)ap0; ap0 += 32;
        if (xv1) { ar1 = *(const uint4*)ap1; ap1 += 32; }

        for (int kt = 0; kt < INTER / 32; ++kt) {
            char* buf = smem + (kt & 1) * BUFB;
#pragma unroll
            for (int cc = 0; cc < 4; ++cc)
                *(uint2*)(buf + wldso + cc * ROWB) =
                    pack4(wreg[0][cc], wreg[1][cc], wreg[2][cc], wreg[3][cc]);
            *(uint4*)(buf + xldso0) = ar0;
            if (xv1) *(uint4*)(buf + xldso1) = ar1;
            __syncthreads();
            if (kt + 1 < INTER / 32) {
#pragma unroll
                for (int i = 0; i < 4; ++i) wreg[i] = *(const float4*)(wp + (size_t)i * HIDDEN);
                wp += (size_t)32 * HIDDEN;
                ar0 = *(const uint4*)ap0; ap0 += 32;
                if (xv1) { ar1 = *(const uint4*)ap1; ap1 += 32; }
            }
            shortx8 bfr[2];
            bfr[0] = *(const shortx8*)(buf + ((2 * w + 0) * 16 + r16) * ROWB + q * 16);
            bfr[1] = *(const shortx8*)(buf + ((2 * w + 1) * 16 + r16) * ROWB + q * 16);
            shortx8 afr[6];
#pragma unroll
            for (int ms = 0; ms < 6; ++ms)
                afr[ms] = *(const shortx8*)(buf + XOFF + (ms * 16 + r16) * ROWB + q * 16);
#pragma unroll
            for (int ms = 0; ms < 6; ++ms) {
                acc[ms][0] = __builtin_amdgcn_mfma_f32_16x16x32_bf16(afr[ms], bfr[0], acc[ms][0], 0, 0, 0);
                acc[ms][1] = __builtin_amdgcn_mfma_f32_16x16x32_bf16(afr[ms], bfr[1], acc[ms][1], 0, 0, 0);
            }
            __syncthreads();
        }
#pragma unroll
        for (int ms = 0; ms < 6; ++ms) {
#pragma unroll
            for (int rr = 0; rr < 4; ++rr) {
                int ml = ms * 16 + 4 * q + rr;
                int p = m0 + ml;
                if (p < n) {
                    int tok = bucket_tok[e * NTOK + p];
                    float* orow = out + (size_t)tok * HIDDEN;
#pragma unroll
                    for (int s = 0; s < 2; ++s) {
                        int col = c0 + (2 * w + s) * 16 + r16;
                        unsafeAtomicAdd(&orow[col], acc[ms][s][rr]);
                    }
                }
            }
        }
    }
}

extern "C" void kernel_launch(void* const* d_in, const int* in_sizes, int n_in,
                              void* d_out, int out_size, void* d_ws, size_t ws_size,
                              hipStream_t stream) {
    const float* x = (const float*)d_in[0];
    const float* wr = (const float*)d_in[1];
    const float* wg = (const float*)d_in[2];
    const float* wu = (const float*)d_in[3];
    const float* wd = (const float*)d_in[4];
    float* out = (float*)d_out;

    char* ws = (char*)d_ws;
    size_t off = 0;
    auto alloc = [&](size_t bytes) {
        void* p = ws + off;
        off = (off + bytes + 255) & ~(size_t)255;
        return p;
    };
    int* topk_idx = (int*)alloc(NTOK * TOPK * sizeof(int));
    float* gates = (float*)alloc(NTOK * TOPK * sizeof(float));
    int* bucket_tok = (int*)alloc(NEXP * NTOK * sizeof(int));
    float* bucket_gate = (float*)alloc(NEXP * NTOK * sizeof(float));
    int* count = (int*)alloc(NEXP * sizeof(int));
    int* base = (int*)alloc(NEXP * sizeof(int));
    __hip_bfloat16* Aws = (__hip_bfloat16*)alloc((size_t)AWS_ROWS * INTER * sizeof(__hip_bfloat16));
    __hip_bfloat16* xbf = (__hip_bfloat16*)alloc((size_t)NTOK * HIDDEN * sizeof(__hip_bfloat16));
    (void)ws_size;

    hipMemsetAsync(d_out, 0, (size_t)NTOK * HIDDEN * sizeof(float), stream);

    xcvt_kernel<<<NTOK * HIDDEN / 4 / 256, 256, 0, stream>>>(x, xbf);
    router_topk_kernel<<<NTOK, 64, 0, stream>>>(x, wr, topk_idx, gates);
    build_buckets_kernel<<<NEXP, 256, 0, stream>>>(topk_idx, gates, bucket_tok, bucket_gate, count);
    base_scan_kernel<<<1, 64, 0, stream>>>(count, base);
    gateup_mfma<<<NEXP * 16, 256, 0, stream>>>(xbf, wg, wu, bucket_tok, bucket_gate, count, base, Aws);
    down_mfma<<<NEXP * 16, 256, 0, stream>>>(Aws, wd, bucket_tok, count, base, out);
}

// Round 6
// 429.657 us; speedup vs baseline: 1.1285x; 1.0188x over previous
//
#include <hip/hip_runtime.h>
#include <hip/hip_bf16.h>
#include <math.h>

#define HIDDEN 2048
#define INTER 1024
#define NEXP 64
#define TOPK 8
#define NTOK 512

#define MT 96                  // M tile rows (6 x 16)
#define ROWB 80                // LDS row stride bytes (32 bf16 = 64B + 16B pad)
#define WROWS 512              // W^T rows per buffer
#define WTB (WROWS * ROWB)     // 40960
#define XOFF WTB
#define BUFB (WTB + MT * ROWB) // 48640 per buffer; x2 = 97280 B LDS
#define AWS_ROWS (NTOK * TOPK + 128)

typedef float floatx4 __attribute__((ext_vector_type(4)));
typedef short shortx8 __attribute__((ext_vector_type(8)));

__device__ __forceinline__ unsigned short bfbits(float f) {
    union { __hip_bfloat16 h; unsigned short u; } c;
    c.h = __float2bfloat16(f);
    return c.u;
}
// pack 4 floats (k-ascending) -> 8B of bf16, k-ascending in memory
__device__ __forceinline__ uint2 pack4(float a, float b, float c, float d) {
    uint2 r;
    r.x = ((unsigned)bfbits(b) << 16) | (unsigned)bfbits(a);
    r.y = ((unsigned)bfbits(d) << 16) | (unsigned)bfbits(c);
    return r;
}

// ---------------- x fp32 -> bf16 pre-convert ----------------
__global__ void xcvt_kernel(const float* __restrict__ x, __hip_bfloat16* __restrict__ xbf) {
    int i = blockIdx.x * blockDim.x + threadIdx.x;
    float4 v = ((const float4*)x)[i];
    ((uint2*)xbf)[i] = pack4(v.x, v.y, v.z, v.w);
}

// ---------------- Router + top-8 + softmax ----------------
__global__ void router_topk_kernel(const float* __restrict__ x,
                                   const float* __restrict__ wr,
                                   int* __restrict__ topk_idx,
                                   float* __restrict__ gates) {
    const int t = blockIdx.x;
    const int lane = threadIdx.x;
    __shared__ float sx[HIDDEN];
    for (int i = lane; i < HIDDEN / 4; i += 64)
        *(float4*)&sx[i * 4] = *(const float4*)(x + (size_t)t * HIDDEN + i * 4);
    __syncthreads();

    float a0 = 0.f, a1 = 0.f, a2 = 0.f, a3 = 0.f;
#pragma unroll 4
    for (int d = 0; d < HIDDEN; d += 4) {
        a0 = fmaf(sx[d + 0], wr[(d + 0) * NEXP + lane], a0);
        a1 = fmaf(sx[d + 1], wr[(d + 1) * NEXP + lane], a1);
        a2 = fmaf(sx[d + 2], wr[(d + 2) * NEXP + lane], a2);
        a3 = fmaf(sx[d + 3], wr[(d + 3) * NEXP + lane], a3);
    }
    float cur = (a0 + a1) + (a2 + a3);

    float topv[TOPK];
    int topi[TOPK];
#pragma unroll
    for (int k = 0; k < TOPK; ++k) {
        float bv = cur;
        int bi = lane;
#pragma unroll
        for (int off = 32; off > 0; off >>= 1) {
            float ov = __shfl_xor(bv, off, 64);
            int oi = __shfl_xor(bi, off, 64);
            if (ov > bv || (ov == bv && oi < bi)) { bv = ov; bi = oi; }
        }
        topv[k] = bv;
        topi[k] = bi;
        if (lane == bi) cur = -INFINITY;
    }
    if (lane == 0) {
        float m = topv[0];
        float ex[TOPK], s = 0.f;
#pragma unroll
        for (int k = 0; k < TOPK; ++k) { ex[k] = __expf(topv[k] - m); s += ex[k]; }
        float inv = 1.f / s;
#pragma unroll
        for (int k = 0; k < TOPK; ++k) {
            gates[t * TOPK + k] = ex[k] * inv;
            topk_idx[t * TOPK + k] = topi[k];
        }
    }
}

// ---------------- Deterministic bucket build ----------------
__global__ void build_buckets_kernel(const int* __restrict__ topk_idx,
                                     const float* __restrict__ gates,
                                     int* __restrict__ bucket_tok,
                                     float* __restrict__ bucket_gate,
                                     int* __restrict__ count) {
    const int e = blockIdx.x;
    const int tid = threadIdx.x;
    __shared__ int scan[256];
    const int t0 = tid * 2;
    int f0 = 0, f1 = 0;
    float g0 = 0.f, g1 = 0.f;
#pragma unroll
    for (int k = 0; k < TOPK; ++k) {
        if (topk_idx[t0 * TOPK + k] == e) { f0 = 1; g0 = gates[t0 * TOPK + k]; }
        if (topk_idx[(t0 + 1) * TOPK + k] == e) { f1 = 1; g1 = gates[(t0 + 1) * TOPK + k]; }
    }
    int s = f0 + f1;
    scan[tid] = s;
    __syncthreads();
    for (int off = 1; off < 256; off <<= 1) {
        int add = (tid >= off) ? scan[tid - off] : 0;
        __syncthreads();
        scan[tid] += add;
        __syncthreads();
    }
    int excl = scan[tid] - s;
    if (f0) { bucket_tok[e * NTOK + excl] = t0; bucket_gate[e * NTOK + excl] = g0; }
    if (f1) { bucket_tok[e * NTOK + excl + f0] = t0 + 1; bucket_gate[e * NTOK + excl + f0] = g1; }
    if (tid == 255) count[e] = scan[255];
}

__global__ void base_scan_kernel(const int* __restrict__ count, int* __restrict__ base) {
    if (threadIdx.x == 0) {
        int acc = 0;
        for (int e = 0; e < NEXP; ++e) { base[e] = acc; acc += count[e]; }
    }
}

// ---------------- Fused gate/up + SiLU (bf16 MFMA, fat chunks) ----------------
// grid 256: e = bid&63 (expert -> XCD e%8), chunk = bid>>6 covers 256 gate +
// 256 up cols. 512 threads = 8 waves; wave w owns gate subtiles {2w,2w+1}
// and up subtiles {2w,2w+1}. LDS W^T rows 0..255 gate cols, 256..511 up cols,
// 32 bf16 k-contiguous per row. Per k-row each wave-instr reads 1KB contiguous.
// Depth-2 register prefetch; raw s_barrier (no vmcnt drain) keeps the next
// K-step's HBM loads in flight across barriers.
__global__ __launch_bounds__(512, 1) void gateup_mfma(
    const __hip_bfloat16* __restrict__ xbf, const float* __restrict__ wg,
    const float* __restrict__ wu, const int* __restrict__ bucket_tok,
    const float* __restrict__ bucket_gate, const int* __restrict__ count,
    const int* __restrict__ base, __hip_bfloat16* __restrict__ Aws) {
    const int e = blockIdx.x & 63;
    const int c0 = (blockIdx.x >> 6) * 256;
    const int n = count[e];
    if (n == 0) return;
    const int b0 = base[e];

    __shared__ char smem[2 * BUFB] __attribute__((aligned(16)));

    const int tid = threadIdx.x;
    const int lane = tid & 63, w = tid >> 6;      // w 0..7
    const int q = lane >> 4, r16 = lane & 15;

    // W staging: 1024 slots (2/thread): slot -> (colgrp 0..127, kq 0..7)
    // colgrp<64 -> gate cols, >=64 -> up cols; LDS row = colgrp*4+cc (uniform).
    const float* wsrc[2];
    unsigned wldso[2];
#pragma unroll
    for (int i = 0; i < 2; ++i) {
        int slot = i * 512 + tid;
        int cg = slot & 127, kq = slot >> 7;
        const float* bp = (cg < 64) ? (wg + (size_t)e * HIDDEN * INTER + c0 + cg * 4)
                                    : (wu + (size_t)e * HIDDEN * INTER + c0 + (cg - 64) * 4);
        wsrc[i] = bp + (size_t)(kq * 4) * INTER;
        wldso[i] = (unsigned)((cg * 4) * ROWB + kq * 8);
    }
    // X staging: 384 slots (tid<384): row 0..95, ch 0..3 (16B chunks)
    const bool xv = tid < 384;
    const int xrow = tid >> 2, xch = tid & 3;
    const unsigned xldso = (unsigned)(XOFF + xrow * ROWB + xch * 16);

    for (int m0 = 0; m0 < n; m0 += MT) {
        int px = m0 + xrow;
        int tok = (xv && px < n) ? bucket_tok[e * NTOK + px] : 0;
        const __hip_bfloat16* xp = xbf + (size_t)tok * HIDDEN + xch * 8;

        floatx4 acc[6][4];
#pragma unroll
        for (int ms = 0; ms < 6; ++ms)
#pragma unroll
            for (int s = 0; s < 4; ++s) acc[ms][s] = (floatx4){0.f, 0.f, 0.f, 0.f};

        float4 wrA[2][4], wrB[2][4];
        uint4 xrA, xrB;

        auto issueA = [&](int kt) {
#pragma unroll
            for (int i = 0; i < 2; ++i)
#pragma unroll
                for (int j = 0; j < 4; ++j)
                    wrA[i][j] = *(const float4*)(wsrc[i] + (size_t)kt * 32 * INTER + (size_t)j * INTER);
            if (xv) xrA = *(const uint4*)(xp + kt * 32);
        };
        auto issueB = [&](int kt) {
#pragma unroll
            for (int i = 0; i < 2; ++i)
#pragma unroll
                for (int j = 0; j < 4; ++j)
                    wrB[i][j] = *(const float4*)(wsrc[i] + (size_t)kt * 32 * INTER + (size_t)j * INTER);
            if (xv) xrB = *(const uint4*)(xp + kt * 32);
        };
        auto writeLDS = [&](char* buf, float4 (&wr_)[2][4], uint4& xr_) {
#pragma unroll
            for (int i = 0; i < 2; ++i)
#pragma unroll
                for (int cc = 0; cc < 4; ++cc)
                    *(uint2*)(buf + wldso[i] + cc * ROWB) =
                        pack4(wr_[i][0][cc], wr_[i][1][cc], wr_[i][2][cc], wr_[i][3][cc]);
            if (xv) *(uint4*)(buf + xldso) = xr_;
        };
        auto compute = [&](const char* buf) {
            shortx8 bfr[4];
#pragma unroll
            for (int s = 0; s < 2; ++s) {
                bfr[s]     = *(const shortx8*)(buf + ((2 * w + s) * 16 + r16) * ROWB + q * 16);
                bfr[2 + s] = *(const shortx8*)(buf + ((256 + (2 * w + s) * 16) + r16) * ROWB + q * 16);
            }
            shortx8 afr[6];
#pragma unroll
            for (int ms = 0; ms < 6; ++ms)
                afr[ms] = *(const shortx8*)(buf + XOFF + (ms * 16 + r16) * ROWB + q * 16);
#pragma unroll
            for (int ms = 0; ms < 6; ++ms)
#pragma unroll
                for (int s = 0; s < 4; ++s)
                    acc[ms][s] = __builtin_amdgcn_mfma_f32_16x16x32_bf16(afr[ms], bfr[s], acc[ms][s], 0, 0, 0);
        };

        issueA(0);
        issueB(1);
        for (int kt2 = 0; kt2 < (HIDDEN / 32) / 2; ++kt2) {
            const int kt = 2 * kt2;
            writeLDS(smem, wrA, xrA);                       // waits vmcnt on bank A only
            asm volatile("s_waitcnt lgkmcnt(0)" ::: "memory");
            __builtin_amdgcn_s_barrier();
            if (kt + 2 < HIDDEN / 32) issueA(kt + 2);       // prefetch depth 2
            compute(smem);
            __builtin_amdgcn_s_barrier();
            writeLDS(smem + BUFB, wrB, xrB);
            asm volatile("s_waitcnt lgkmcnt(0)" ::: "memory");
            __builtin_amdgcn_s_barrier();
            if (kt + 3 < HIDDEN / 32) issueB(kt + 3);
            compute(smem + BUFB);
            __builtin_amdgcn_s_barrier();
        }

        // epilogue: A = silu(h) * u * gate, bf16
        // C layout: col = lane&15, row = 4*(lane>>4) + reg (m89-verified)
#pragma unroll
        for (int ms = 0; ms < 6; ++ms) {
#pragma unroll
            for (int j = 0; j < 2; ++j) {
                floatx4 h4 = acc[ms][j], u4 = acc[ms][j + 2];
#pragma unroll
                for (int rr = 0; rr < 4; ++rr) {
                    int ml = ms * 16 + 4 * q + rr;
                    int p = m0 + ml;
                    if (p < n) {
                        float gt = bucket_gate[e * NTOK + p];
                        float hv = h4[rr];
                        float av = hv / (1.f + __expf(-hv)) * u4[rr] * gt;
                        int col = c0 + (2 * w + j) * 16 + r16;
                        Aws[(size_t)(b0 + p) * INTER + col] = __float2bfloat16(av);
                    }
                }
            }
        }
    }
}

// ---------------- Down projection (bf16 MFMA, fat chunks) + scatter-add ----------------
// grid 256: e = bid&63, chunk = bid>>6 covers 512 out cols (2KB contiguous per
// W-row visit). 512 threads; wave w owns col-subtiles {4w..4w+3}.
__global__ __launch_bounds__(512, 1) void down_mfma(
    const __hip_bfloat16* __restrict__ Aws, const float* __restrict__ wd,
    const int* __restrict__ bucket_tok, const int* __restrict__ count,
    const int* __restrict__ base, float* __restrict__ out) {
    const int e = blockIdx.x & 63;
    const int c0 = (blockIdx.x >> 6) * 512;
    const int n = count[e];
    if (n == 0) return;
    const int b0 = base[e];

    __shared__ char smem[2 * BUFB] __attribute__((aligned(16)));

    const int tid = threadIdx.x;
    const int lane = tid & 63, w = tid >> 6;
    const int q = lane >> 4, r16 = lane & 15;

    const float* wsrc[2];
    unsigned wldso[2];
#pragma unroll
    for (int i = 0; i < 2; ++i) {
        int slot = i * 512 + tid;
        int cg = slot & 127, kq = slot >> 7;
        wsrc[i] = wd + (size_t)e * INTER * HIDDEN + c0 + cg * 4 + (size_t)(kq * 4) * HIDDEN;
        wldso[i] = (unsigned)((cg * 4) * ROWB + kq * 8);
    }
    const bool xv = tid < 384;
    const int xrow = tid >> 2, xch = tid & 3;
    const unsigned xldso = (unsigned)(XOFF + xrow * ROWB + xch * 16);

    for (int m0 = 0; m0 < n; m0 += MT) {
        const __hip_bfloat16* ap = Aws + (size_t)(b0 + m0 + xrow) * INTER + xch * 8;

        floatx4 acc[6][4];
#pragma unroll
        for (int ms = 0; ms < 6; ++ms)
#pragma unroll
            for (int s = 0; s < 4; ++s) acc[ms][s] = (floatx4){0.f, 0.f, 0.f, 0.f};

        float4 wrA[2][4], wrB[2][4];
        uint4 arA, arB;

        auto issueA = [&](int kt) {
#pragma unroll
            for (int i = 0; i < 2; ++i)
#pragma unroll
                for (int j = 0; j < 4; ++j)
                    wrA[i][j] = *(const float4*)(wsrc[i] + (size_t)kt * 32 * HIDDEN + (size_t)j * HIDDEN);
            if (xv) arA = *(const uint4*)(ap + kt * 32);
        };
        auto issueB = [&](int kt) {
#pragma unroll
            for (int i = 0; i < 2; ++i)
#pragma unroll
                for (int j = 0; j < 4; ++j)
                    wrB[i][j] = *(const float4*)(wsrc[i] + (size_t)kt * 32 * HIDDEN + (size_t)j * HIDDEN);
            if (xv) arB = *(const uint4*)(ap + kt * 32);
        };
        auto writeLDS = [&](char* buf, float4 (&wr_)[2][4], uint4& ar_) {
#pragma unroll
            for (int i = 0; i < 2; ++i)
#pragma unroll
                for (int cc = 0; cc < 4; ++cc)
                    *(uint2*)(buf + wldso[i] + cc * ROWB) =
                        pack4(wr_[i][0][cc], wr_[i][1][cc], wr_[i][2][cc], wr_[i][3][cc]);
            if (xv) *(uint4*)(buf + xldso) = ar_;
        };
        auto compute = [&](const char* buf) {
            shortx8 bfr[4];
#pragma unroll
            for (int s = 0; s < 4; ++s)
                bfr[s] = *(const shortx8*)(buf + ((4 * w + s) * 16 + r16) * ROWB + q * 16);
            shortx8 afr[6];
#pragma unroll
            for (int ms = 0; ms < 6; ++ms)
                afr[ms] = *(const shortx8*)(buf + XOFF + (ms * 16 + r16) * ROWB + q * 16);
#pragma unroll
            for (int ms = 0; ms < 6; ++ms)
#pragma unroll
                for (int s = 0; s < 4; ++s)
                    acc[ms][s] = __builtin_amdgcn_mfma_f32_16x16x32_bf16(afr[ms], bfr[s], acc[ms][s], 0, 0, 0);
        };

        issueA(0);
        issueB(1);
        for (int kt2 = 0; kt2 < (INTER / 32) / 2; ++kt2) {
            const int kt = 2 * kt2;
            writeLDS(smem, wrA, arA);
            asm volatile("s_waitcnt lgkmcnt(0)" ::: "memory");
            __builtin_amdgcn_s_barrier();
            if (kt + 2 < INTER / 32) issueA(kt + 2);
            compute(smem);
            __builtin_amdgcn_s_barrier();
            writeLDS(smem + BUFB, wrB, arB);
            asm volatile("s_waitcnt lgkmcnt(0)" ::: "memory");
            __builtin_amdgcn_s_barrier();
            if (kt + 3 < INTER / 32) issueB(kt + 3);
            compute(smem + BUFB);
            __builtin_amdgcn_s_barrier();
        }

#pragma unroll
        for (int ms = 0; ms < 6; ++ms) {
#pragma unroll
            for (int rr = 0; rr < 4; ++rr) {
                int ml = ms * 16 + 4 * q + rr;
                int p = m0 + ml;
                if (p < n) {
                    int tok = bucket_tok[e * NTOK + p];
                    float* orow = out + (size_t)tok * HIDDEN;
#pragma unroll
                    for (int s = 0; s < 4; ++s) {
                        int col = c0 + (4 * w + s) * 16 + r16;
                        unsafeAtomicAdd(&orow[col], acc[ms][s][rr]);
                    }
                }
            }
        }
    }
}

extern "C" void kernel_launch(void* const* d_in, const int* in_sizes, int n_in,
                              void* d_out, int out_size, void* d_ws, size_t ws_size,
                              hipStream_t stream) {
    const float* x = (const float*)d_in[0];
    const float* wr = (const float*)d_in[1];
    const float* wg = (const float*)d_in[2];
    const float* wu = (const float*)d_in[3];
    const float* wd = (const float*)d_in[4];
    float* out = (float*)d_out;

    char* ws = (char*)d_ws;
    size_t off = 0;
    auto alloc = [&](size_t bytes) {
        void* p = ws + off;
        off = (off + bytes + 255) & ~(size_t)255;
        return p;
    };
    int* topk_idx = (int*)alloc(NTOK * TOPK * sizeof(int));
    float* gates = (float*)alloc(NTOK * TOPK * sizeof(float));
    int* bucket_tok = (int*)alloc(NEXP * NTOK * sizeof(int));
    float* bucket_gate = (float*)alloc(NEXP * NTOK * sizeof(float));
    int* count = (int*)alloc(NEXP * sizeof(int));
    int* base = (int*)alloc(NEXP * sizeof(int));
    __hip_bfloat16* Aws = (__hip_bfloat16*)alloc((size_t)AWS_ROWS * INTER * sizeof(__hip_bfloat16));
    __hip_bfloat16* xbf = (__hip_bfloat16*)alloc((size_t)NTOK * HIDDEN * sizeof(__hip_bfloat16));
    (void)ws_size;

    hipMemsetAsync(d_out, 0, (size_t)NTOK * HIDDEN * sizeof(float), stream);

    xcvt_kernel<<<NTOK * HIDDEN / 4 / 256, 256, 0, stream>>>(x, xbf);
    router_topk_kernel<<<NTOK, 64, 0, stream>>>(x, wr, topk_idx, gates);
    build_buckets_kernel<<<NEXP, 256, 0, stream>>>(topk_idx, gates, bucket_tok, bucket_gate, count);
    base_scan_kernel<<<1, 64, 0, stream>>>(count, base);
    gateup_mfma<<<NEXP * 4, 512, 0, stream>>>(xbf, wg, wu, bucket_tok, bucket_gate, count, base, Aws);
    down_mfma<<<NEXP * 4, 512, 0, stream>>>(Aws, wd, bucket_tok, count, base, out);
}

// Round 7
// 425.773 us; speedup vs baseline: 1.1387x; 1.0091x over previous
//
#include <hip/hip_runtime.h>
#include <hip/hip_bf16.h>
#include <math.h>

#define HIDDEN 2048
#define INTER 1024
#define NEXP 64
#define TOPK 8
#define NTOK 512

#define MT 96                  // M tile rows (6 x 16)
#define ROWB 80                // LDS row stride bytes (32 bf16 = 64B + 16B pad)
#define WROWS 512              // W^T rows per buffer
#define WTB (WROWS * ROWB)     // 40960
#define XOFF WTB
#define BUFB (WTB + MT * ROWB) // 48640 per buffer; x2 = 97280 B LDS
#define AWS_ROWS (NTOK * TOPK + 128)

typedef float floatx4 __attribute__((ext_vector_type(4)));
typedef short shortx8 __attribute__((ext_vector_type(8)));

__device__ __forceinline__ unsigned short bfbits(float f) {
    union { __hip_bfloat16 h; unsigned short u; } c;
    c.h = __float2bfloat16(f);
    return c.u;
}
// pack 4 floats (k-ascending) -> 8B of bf16, k-ascending in memory
__device__ __forceinline__ uint2 pack4(float a, float b, float c, float d) {
    uint2 r;
    r.x = ((unsigned)bfbits(b) << 16) | (unsigned)bfbits(a);
    r.y = ((unsigned)bfbits(d) << 16) | (unsigned)bfbits(c);
    return r;
}

// ---------------- x fp32 -> bf16 pre-convert ----------------
__global__ void xcvt_kernel(const float* __restrict__ x, __hip_bfloat16* __restrict__ xbf) {
    int i = blockIdx.x * blockDim.x + threadIdx.x;
    float4 v = ((const float4*)x)[i];
    ((uint2*)xbf)[i] = pack4(v.x, v.y, v.z, v.w);
}

// ---------------- Router + top-8 + softmax ----------------
__global__ void router_topk_kernel(const float* __restrict__ x,
                                   const float* __restrict__ wr,
                                   int* __restrict__ topk_idx,
                                   float* __restrict__ gates) {
    const int t = blockIdx.x;
    const int lane = threadIdx.x;
    __shared__ float sx[HIDDEN];
    for (int i = lane; i < HIDDEN / 4; i += 64)
        *(float4*)&sx[i * 4] = *(const float4*)(x + (size_t)t * HIDDEN + i * 4);
    __syncthreads();

    float a0 = 0.f, a1 = 0.f, a2 = 0.f, a3 = 0.f;
#pragma unroll 4
    for (int d = 0; d < HIDDEN; d += 4) {
        a0 = fmaf(sx[d + 0], wr[(d + 0) * NEXP + lane], a0);
        a1 = fmaf(sx[d + 1], wr[(d + 1) * NEXP + lane], a1);
        a2 = fmaf(sx[d + 2], wr[(d + 2) * NEXP + lane], a2);
        a3 = fmaf(sx[d + 3], wr[(d + 3) * NEXP + lane], a3);
    }
    float cur = (a0 + a1) + (a2 + a3);

    float topv[TOPK];
    int topi[TOPK];
#pragma unroll
    for (int k = 0; k < TOPK; ++k) {
        float bv = cur;
        int bi = lane;
#pragma unroll
        for (int off = 32; off > 0; off >>= 1) {
            float ov = __shfl_xor(bv, off, 64);
            int oi = __shfl_xor(bi, off, 64);
            if (ov > bv || (ov == bv && oi < bi)) { bv = ov; bi = oi; }
        }
        topv[k] = bv;
        topi[k] = bi;
        if (lane == bi) cur = -INFINITY;
    }
    if (lane == 0) {
        float m = topv[0];
        float ex[TOPK], s = 0.f;
#pragma unroll
        for (int k = 0; k < TOPK; ++k) { ex[k] = __expf(topv[k] - m); s += ex[k]; }
        float inv = 1.f / s;
#pragma unroll
        for (int k = 0; k < TOPK; ++k) {
            gates[t * TOPK + k] = ex[k] * inv;
            topk_idx[t * TOPK + k] = topi[k];
        }
    }
}

// ---------------- Deterministic bucket build ----------------
__global__ void build_buckets_kernel(const int* __restrict__ topk_idx,
                                     const float* __restrict__ gates,
                                     int* __restrict__ bucket_tok,
                                     float* __restrict__ bucket_gate,
                                     int* __restrict__ count) {
    const int e = blockIdx.x;
    const int tid = threadIdx.x;
    __shared__ int scan[256];
    const int t0 = tid * 2;
    int f0 = 0, f1 = 0;
    float g0 = 0.f, g1 = 0.f;
#pragma unroll
    for (int k = 0; k < TOPK; ++k) {
        if (topk_idx[t0 * TOPK + k] == e) { f0 = 1; g0 = gates[t0 * TOPK + k]; }
        if (topk_idx[(t0 + 1) * TOPK + k] == e) { f1 = 1; g1 = gates[(t0 + 1) * TOPK + k]; }
    }
    int s = f0 + f1;
    scan[tid] = s;
    __syncthreads();
    for (int off = 1; off < 256; off <<= 1) {
        int add = (tid >= off) ? scan[tid - off] : 0;
        __syncthreads();
        scan[tid] += add;
        __syncthreads();
    }
    int excl = scan[tid] - s;
    if (f0) { bucket_tok[e * NTOK + excl] = t0; bucket_gate[e * NTOK + excl] = g0; }
    if (f1) { bucket_tok[e * NTOK + excl + f0] = t0 + 1; bucket_gate[e * NTOK + excl + f0] = g1; }
    if (tid == 255) count[e] = scan[255];
}

__global__ void base_scan_kernel(const int* __restrict__ count, int* __restrict__ base) {
    if (threadIdx.x == 0) {
        int acc = 0;
        for (int e = 0; e < NEXP; ++e) { base[e] = acc; acc += count[e]; }
    }
}

// ---------------- Fused gate/up + SiLU (bf16 MFMA, fat chunks) ----------------
// grid 256: e = bid&63 (expert -> XCD e%8), chunk = bid>>6 covers 256 gate +
// 256 up cols. 512 threads = 8 waves; wave w owns gate subtiles {2w,2w+1}
// and up subtiles {2w,2w+1}. LDS W^T rows 0..255 gate cols, 256..511 up cols,
// 32 bf16 k-contiguous per row.
// W staging decode (CONFLICT-FREE): slot = i*512+tid -> cg = slot>>3 (col
// group of 4), kq = slot&7 (k-quad). An 8-lane group writes the SAME LDS row
// at kq*8 byte steps (contiguous 64B) -> 4 lanes/bank per b64 write = 0
// conflicts (R5/R6 mapping was 320B lane stride = 2 banks = 32-way).
// Global side: per instr, 8 lanes read 128B contiguous per W row x 8 rows.
__global__ __launch_bounds__(512, 1) void gateup_mfma(
    const __hip_bfloat16* __restrict__ xbf, const float* __restrict__ wg,
    const float* __restrict__ wu, const int* __restrict__ bucket_tok,
    const float* __restrict__ bucket_gate, const int* __restrict__ count,
    const int* __restrict__ base, __hip_bfloat16* __restrict__ Aws) {
    const int e = blockIdx.x & 63;
    const int c0 = (blockIdx.x >> 6) * 256;
    const int n = count[e];
    if (n == 0) return;
    const int b0 = base[e];

    __shared__ char smem[2 * BUFB] __attribute__((aligned(16)));

    const int tid = threadIdx.x;
    const int lane = tid & 63, w = tid >> 6;      // w 0..7
    const int q = lane >> 4, r16 = lane & 15;

    // W staging: 1024 slots (2/thread): slot -> (cg 0..127, kq 0..7)
    const float* wsrc[2];
    unsigned wldso[2];
#pragma unroll
    for (int i = 0; i < 2; ++i) {
        int slot = i * 512 + tid;
        int cg = slot >> 3, kq = slot & 7;
        const float* bp = (cg < 64) ? (wg + (size_t)e * HIDDEN * INTER + c0 + cg * 4)
                                    : (wu + (size_t)e * HIDDEN * INTER + c0 + (cg - 64) * 4);
        wsrc[i] = bp + (size_t)(kq * 4) * INTER;
        wldso[i] = (unsigned)((cg * 4) * ROWB + kq * 8);
    }
    // X staging: 384 slots (tid<384): row 0..95, ch 0..3 (16B chunks)
    const bool xv = tid < 384;
    const int xrow = tid >> 2, xch = tid & 3;
    const unsigned xldso = (unsigned)(XOFF + xrow * ROWB + xch * 16);

    for (int m0 = 0; m0 < n; m0 += MT) {
        int px = m0 + xrow;
        int tok = (xv && px < n) ? bucket_tok[e * NTOK + px] : 0;
        const __hip_bfloat16* xp = xbf + (size_t)tok * HIDDEN + xch * 8;

        floatx4 acc[6][4];
#pragma unroll
        for (int ms = 0; ms < 6; ++ms)
#pragma unroll
            for (int s = 0; s < 4; ++s) acc[ms][s] = (floatx4){0.f, 0.f, 0.f, 0.f};

        float4 wrA[2][4], wrB[2][4];
        uint4 xrA, xrB;

        auto issueA = [&](int kt) {
#pragma unroll
            for (int i = 0; i < 2; ++i)
#pragma unroll
                for (int j = 0; j < 4; ++j)
                    wrA[i][j] = *(const float4*)(wsrc[i] + (size_t)kt * 32 * INTER + (size_t)j * INTER);
            if (xv) xrA = *(const uint4*)(xp + kt * 32);
        };
        auto issueB = [&](int kt) {
#pragma unroll
            for (int i = 0; i < 2; ++i)
#pragma unroll
                for (int j = 0; j < 4; ++j)
                    wrB[i][j] = *(const float4*)(wsrc[i] + (size_t)kt * 32 * INTER + (size_t)j * INTER);
            if (xv) xrB = *(const uint4*)(xp + kt * 32);
        };
        auto writeLDS = [&](char* buf, float4 (&wr_)[2][4], uint4& xr_) {
#pragma unroll
            for (int i = 0; i < 2; ++i)
#pragma unroll
                for (int cc = 0; cc < 4; ++cc)
                    *(uint2*)(buf + wldso[i] + cc * ROWB) =
                        pack4(wr_[i][0][cc], wr_[i][1][cc], wr_[i][2][cc], wr_[i][3][cc]);
            if (xv) *(uint4*)(buf + xldso) = xr_;
        };
        auto compute = [&](const char* buf) {
            shortx8 bfr[4];
#pragma unroll
            for (int s = 0; s < 2; ++s) {
                bfr[s]     = *(const shortx8*)(buf + ((2 * w + s) * 16 + r16) * ROWB + q * 16);
                bfr[2 + s] = *(const shortx8*)(buf + ((256 + (2 * w + s) * 16) + r16) * ROWB + q * 16);
            }
            shortx8 afr[6];
#pragma unroll
            for (int ms = 0; ms < 6; ++ms)
                afr[ms] = *(const shortx8*)(buf + XOFF + (ms * 16 + r16) * ROWB + q * 16);
#pragma unroll
            for (int ms = 0; ms < 6; ++ms)
#pragma unroll
                for (int s = 0; s < 4; ++s)
                    acc[ms][s] = __builtin_amdgcn_mfma_f32_16x16x32_bf16(afr[ms], bfr[s], acc[ms][s], 0, 0, 0);
        };

        issueA(0);
        issueB(1);
        for (int kt2 = 0; kt2 < (HIDDEN / 32) / 2; ++kt2) {
            const int kt = 2 * kt2;
            writeLDS(smem, wrA, xrA);                       // waits vmcnt on bank A only
            asm volatile("s_waitcnt lgkmcnt(0)" ::: "memory");
            __builtin_amdgcn_s_barrier();
            if (kt + 2 < HIDDEN / 32) issueA(kt + 2);       // prefetch depth 2
            compute(smem);
            __builtin_amdgcn_s_barrier();
            writeLDS(smem + BUFB, wrB, xrB);
            asm volatile("s_waitcnt lgkmcnt(0)" ::: "memory");
            __builtin_amdgcn_s_barrier();
            if (kt + 3 < HIDDEN / 32) issueB(kt + 3);
            compute(smem + BUFB);
            __builtin_amdgcn_s_barrier();
        }

        // epilogue: A = silu(h) * u * gate, bf16
        // C layout: col = lane&15, row = 4*(lane>>4) + reg (m89-verified)
#pragma unroll
        for (int ms = 0; ms < 6; ++ms) {
#pragma unroll
            for (int j = 0; j < 2; ++j) {
                floatx4 h4 = acc[ms][j], u4 = acc[ms][j + 2];
#pragma unroll
                for (int rr = 0; rr < 4; ++rr) {
                    int ml = ms * 16 + 4 * q + rr;
                    int p = m0 + ml;
                    if (p < n) {
                        float gt = bucket_gate[e * NTOK + p];
                        float hv = h4[rr];
                        float av = hv / (1.f + __expf(-hv)) * u4[rr] * gt;
                        int col = c0 + (2 * w + j) * 16 + r16;
                        Aws[(size_t)(b0 + p) * INTER + col] = __float2bfloat16(av);
                    }
                }
            }
        }
    }
}

// ---------------- Down projection (bf16 MFMA, fat chunks) + scatter-add ----------------
// grid 256: e = bid&63, chunk = bid>>6 covers 512 out cols. 512 threads;
// wave w owns col-subtiles {4w..4w+3}. Same conflict-free staging decode.
__global__ __launch_bounds__(512, 1) void down_mfma(
    const __hip_bfloat16* __restrict__ Aws, const float* __restrict__ wd,
    const int* __restrict__ bucket_tok, const int* __restrict__ count,
    const int* __restrict__ base, float* __restrict__ out) {
    const int e = blockIdx.x & 63;
    const int c0 = (blockIdx.x >> 6) * 512;
    const int n = count[e];
    if (n == 0) return;
    const int b0 = base[e];

    __shared__ char smem[2 * BUFB] __attribute__((aligned(16)));

    const int tid = threadIdx.x;
    const int lane = tid & 63, w = tid >> 6;
    const int q = lane >> 4, r16 = lane & 15;

    const float* wsrc[2];
    unsigned wldso[2];
#pragma unroll
    for (int i = 0; i < 2; ++i) {
        int slot = i * 512 + tid;
        int cg = slot >> 3, kq = slot & 7;
        wsrc[i] = wd + (size_t)e * INTER * HIDDEN + c0 + cg * 4 + (size_t)(kq * 4) * HIDDEN;
        wldso[i] = (unsigned)((cg * 4) * ROWB + kq * 8);
    }
    const bool xv = tid < 384;
    const int xrow = tid >> 2, xch = tid & 3;
    const unsigned xldso = (unsigned)(XOFF + xrow * ROWB + xch * 16);

    for (int m0 = 0; m0 < n; m0 += MT) {
        const __hip_bfloat16* ap = Aws + (size_t)(b0 + m0 + xrow) * INTER + xch * 8;

        floatx4 acc[6][4];
#pragma unroll
        for (int ms = 0; ms < 6; ++ms)
#pragma unroll
            for (int s = 0; s < 4; ++s) acc[ms][s] = (floatx4){0.f, 0.f, 0.f, 0.f};

        float4 wrA[2][4], wrB[2][4];
        uint4 arA, arB;

        auto issueA = [&](int kt) {
#pragma unroll
            for (int i = 0; i < 2; ++i)
#pragma unroll
                for (int j = 0; j < 4; ++j)
                    wrA[i][j] = *(const float4*)(wsrc[i] + (size_t)kt * 32 * HIDDEN + (size_t)j * HIDDEN);
            if (xv) arA = *(const uint4*)(ap + kt * 32);
        };
        auto issueB = [&](int kt) {
#pragma unroll
            for (int i = 0; i < 2; ++i)
#pragma unroll
                for (int j = 0; j < 4; ++j)
                    wrB[i][j] = *(const float4*)(wsrc[i] + (size_t)kt * 32 * HIDDEN + (size_t)j * HIDDEN);
            if (xv) arB = *(const uint4*)(ap + kt * 32);
        };
        auto writeLDS = [&](char* buf, float4 (&wr_)[2][4], uint4& ar_) {
#pragma unroll
            for (int i = 0; i < 2; ++i)
#pragma unroll
                for (int cc = 0; cc < 4; ++cc)
                    *(uint2*)(buf + wldso[i] + cc * ROWB) =
                        pack4(wr_[i][0][cc], wr_[i][1][cc], wr_[i][2][cc], wr_[i][3][cc]);
            if (xv) *(uint4*)(buf + xldso) = ar_;
        };
        auto compute = [&](const char* buf) {
            shortx8 bfr[4];
#pragma unroll
            for (int s = 0; s < 4; ++s)
                bfr[s] = *(const shortx8*)(buf + ((4 * w + s) * 16 + r16) * ROWB + q * 16);
            shortx8 afr[6];
#pragma unroll
            for (int ms = 0; ms < 6; ++ms)
                afr[ms] = *(const shortx8*)(buf + XOFF + (ms * 16 + r16) * ROWB + q * 16);
#pragma unroll
            for (int ms = 0; ms < 6; ++ms)
#pragma unroll
                for (int s = 0; s < 4; ++s)
                    acc[ms][s] = __builtin_amdgcn_mfma_f32_16x16x32_bf16(afr[ms], bfr[s], acc[ms][s], 0, 0, 0);
        };

        issueA(0);
        issueB(1);
        for (int kt2 = 0; kt2 < (INTER / 32) / 2; ++kt2) {
            const int kt = 2 * kt2;
            writeLDS(smem, wrA, arA);
            asm volatile("s_waitcnt lgkmcnt(0)" ::: "memory");
            __builtin_amdgcn_s_barrier();
            if (kt + 2 < INTER / 32) issueA(kt + 2);
            compute(smem);
            __builtin_amdgcn_s_barrier();
            writeLDS(smem + BUFB, wrB, arB);
            asm volatile("s_waitcnt lgkmcnt(0)" ::: "memory");
            __builtin_amdgcn_s_barrier();
            if (kt + 3 < INTER / 32) issueB(kt + 3);
            compute(smem + BUFB);
            __builtin_amdgcn_s_barrier();
        }

#pragma unroll
        for (int ms = 0; ms < 6; ++ms) {
#pragma unroll
            for (int rr = 0; rr < 4; ++rr) {
                int ml = ms * 16 + 4 * q + rr;
                int p = m0 + ml;
                if (p < n) {
                    int tok = bucket_tok[e * NTOK + p];
                    float* orow = out + (size_t)tok * HIDDEN;
#pragma unroll
                    for (int s = 0; s < 4; ++s) {
                        int col = c0 + (4 * w + s) * 16 + r16;
                        unsafeAtomicAdd(&orow[col], acc[ms][s][rr]);
                    }
                }
            }
        }
    }
}

extern "C" void kernel_launch(void* const* d_in, const int* in_sizes, int n_in,
                              void* d_out, int out_size, void* d_ws, size_t ws_size,
                              hipStream_t stream) {
    const float* x = (const float*)d_in[0];
    const float* wr = (const float*)d_in[1];
    const float* wg = (const float*)d_in[2];
    const float* wu = (const float*)d_in[3];
    const float* wd = (const float*)d_in[4];
    float* out = (float*)d_out;

    char* ws = (char*)d_ws;
    size_t off = 0;
    auto alloc = [&](size_t bytes) {
        void* p = ws + off;
        off = (off + bytes + 255) & ~(size_t)255;
        return p;
    };
    int* topk_idx = (int*)alloc(NTOK * TOPK * sizeof(int));
    float* gates = (float*)alloc(NTOK * TOPK * sizeof(float));
    int* bucket_tok = (int*)alloc(NEXP * NTOK * sizeof(int));
    float* bucket_gate = (float*)alloc(NEXP * NTOK * sizeof(float));
    int* count = (int*)alloc(NEXP * sizeof(int));
    int* base = (int*)alloc(NEXP * sizeof(int));
    __hip_bfloat16* Aws = (__hip_bfloat16*)alloc((size_t)AWS_ROWS * INTER * sizeof(__hip_bfloat16));
    __hip_bfloat16* xbf = (__hip_bfloat16*)alloc((size_t)NTOK * HIDDEN * sizeof(__hip_bfloat16));
    (void)ws_size;

    hipMemsetAsync(d_out, 0, (size_t)NTOK * HIDDEN * sizeof(float), stream);

    xcvt_kernel<<<NTOK * HIDDEN / 4 / 256, 256, 0, stream>>>(x, xbf);
    router_topk_kernel<<<NTOK, 64, 0, stream>>>(x, wr, topk_idx, gates);
    build_buckets_kernel<<<NEXP, 256, 0, stream>>>(topk_idx, gates, bucket_tok, bucket_gate, count);
    base_scan_kernel<<<1, 64, 0, stream>>>(count, base);
    gateup_mfma<<<NEXP * 4, 512, 0, stream>>>(xbf, wg, wu, bucket_tok, bucket_gate, count, base, Aws);
    down_mfma<<<NEXP * 4, 512, 0, stream>>>(Aws, wd, bucket_tok, count, base, out);
}